// Round 2
// baseline (3322.950 us; speedup 1.0000x reference)
//
#include <hip/hip_runtime.h>
#include <float.h>
#include <math.h>

// Problem constants (fixed by setup_inputs)
constexpr int Bn = 131072;  // points
constexpr int Dn = 256;     // feature dim
constexpr int Kn = 1024;    // clusters
constexpr int Ln = 526;     // label dim
constexpr float EPSF = 1e-8f;

// GEMM tiling for the assignment kernel
constexpr int BM = 128;     // points per block
constexpr int BN = 128;     // centroids per n-tile
constexpr int BK = 16;      // d-chunk
constexpr int LDT = 132;    // padded LDS row stride (floats) -> 2-way conflicts max
constexpr int NT = Kn / BN; // 8 n-tiles
constexpr int DC = Dn / BK; // 16 d-chunks
constexpr int NTILES = NT * DC; // 128

union SMemU {
    float tiles[2][2][BK][LDT];                 // [buf][A/B][d][m], 33792 B
    struct { float t[BM][16]; int k[BM][16]; } red;
};

// ---------------- prep: c2[k] = sum(centroids[k]^2), rln[k] = sqrt(sum(rl[k]^2))
__global__ __launch_bounds__(256) void prep_kernel(
    const float* __restrict__ centroids, const float* __restrict__ rlabels,
    float* __restrict__ c2, float* __restrict__ rln)
{
    const int k = blockIdx.x;
    const int t = threadIdx.x;
    float v = centroids[k * Dn + t];            // Dn == blockDim
    float s1 = v * v;
    float s2 = 0.f;
    for (int i = t; i < Ln; i += 256) {
        float u = rlabels[(size_t)k * Ln + i];
        s2 += u * u;
    }
    for (int off = 32; off > 0; off >>= 1) {
        s1 += __shfl_down(s1, off, 64);
        s2 += __shfl_down(s2, off, 64);
    }
    __shared__ float red[8];
    const int wv = t >> 6;
    if ((t & 63) == 0) { red[wv * 2] = s1; red[wv * 2 + 1] = s2; }
    __syncthreads();
    if (t == 0) {
        c2[k]  = red[0] + red[2] + red[4] + red[6];
        rln[k] = sqrtf(red[1] + red[3] + red[5] + red[7]);
    }
}

// ---------------- assignment: per-block 128 points x all 1024 centroids
// t(b,k) = c2[k] - 2*dot(p_b, c_k); argmin_k t == argmin_k dist (x2 is row-constant).
__global__ __launch_bounds__(256, 2) void assign_kernel(
    const float* __restrict__ points, const float* __restrict__ centroids,
    const float* __restrict__ c2,
    float* __restrict__ o_assign, int* __restrict__ ws_assign,
    float* __restrict__ ws_tmin)
{
    __shared__ SMemU sm;
    const int tid = threadIdx.x;
    const int tx = tid & 15;          // centroid group
    const int ty = tid >> 4;          // point group
    const int bm0 = blockIdx.x * BM;

    // staging mapping: each thread loads 2 float4 per matrix per tile
    const int r0 = tid >> 2;          // row 0..63
    const int g0 = tid & 3;           // d-group (float4)

    float acc[8][8];
#pragma unroll
    for (int i = 0; i < 8; ++i)
#pragma unroll
        for (int j = 0; j < 8; ++j) acc[i][j] = 0.f;

    float mint[8];
    int   mink[8];
#pragma unroll
    for (int i = 0; i < 8; ++i) { mint[i] = FLT_MAX; mink[i] = 0; }

    float4 pa0, pa1, pb0, pb1;        // prefetch regs

    auto prefetch = [&](int tile) {
        const int nt = tile >> 4, dc = tile & 15;
        const size_t dofs = dc * BK + g0 * 4;
        const float* ap = points    + (size_t)(bm0 + r0) * Dn + dofs;
        const float* bp = centroids + (size_t)(nt * BN + r0) * Dn + dofs;
        pa0 = *(const float4*)(ap);
        pa1 = *(const float4*)(ap + (size_t)64 * Dn);
        pb0 = *(const float4*)(bp);
        pb1 = *(const float4*)(bp + (size_t)64 * Dn);
    };
    auto writeLDS = [&](int buf) {
        float* As = &sm.tiles[buf][0][0][0];
        float* Bs = &sm.tiles[buf][1][0][0];
        const int c0 = g0 * 4;
        As[(c0 + 0) * LDT + r0]      = pa0.x;
        As[(c0 + 1) * LDT + r0]      = pa0.y;
        As[(c0 + 2) * LDT + r0]      = pa0.z;
        As[(c0 + 3) * LDT + r0]      = pa0.w;
        As[(c0 + 0) * LDT + r0 + 64] = pa1.x;
        As[(c0 + 1) * LDT + r0 + 64] = pa1.y;
        As[(c0 + 2) * LDT + r0 + 64] = pa1.z;
        As[(c0 + 3) * LDT + r0 + 64] = pa1.w;
        Bs[(c0 + 0) * LDT + r0]      = pb0.x;
        Bs[(c0 + 1) * LDT + r0]      = pb0.y;
        Bs[(c0 + 2) * LDT + r0]      = pb0.z;
        Bs[(c0 + 3) * LDT + r0]      = pb0.w;
        Bs[(c0 + 0) * LDT + r0 + 64] = pb1.x;
        Bs[(c0 + 1) * LDT + r0 + 64] = pb1.y;
        Bs[(c0 + 2) * LDT + r0 + 64] = pb1.z;
        Bs[(c0 + 3) * LDT + r0 + 64] = pb1.w;
    };

    prefetch(0);
    writeLDS(0);
    __syncthreads();

    for (int tile = 0; tile < NTILES; ++tile) {
        const int buf = tile & 1;
        const bool more = (tile + 1) < NTILES;
        if (more) prefetch(tile + 1);

        const float* As = &sm.tiles[buf][0][0][0];
        const float* Bs = &sm.tiles[buf][1][0][0];
#pragma unroll
        for (int c = 0; c < BK; ++c) {
            const float4 a0 = *(const float4*)(As + c * LDT + 4 * ty);
            const float4 a1 = *(const float4*)(As + c * LDT + 64 + 4 * ty);
            const float4 b0 = *(const float4*)(Bs + c * LDT + 4 * tx);
            const float4 b1 = *(const float4*)(Bs + c * LDT + 64 + 4 * tx);
            const float av[8] = {a0.x, a0.y, a0.z, a0.w, a1.x, a1.y, a1.z, a1.w};
            const float bv[8] = {b0.x, b0.y, b0.z, b0.w, b1.x, b1.y, b1.z, b1.w};
#pragma unroll
            for (int i = 0; i < 8; ++i)
#pragma unroll
                for (int j = 0; j < 8; ++j)
                    acc[i][j] = fmaf(av[i], bv[j], acc[i][j]);
        }

        if ((tile & 15) == 15) {
            // n-tile complete: fold into per-thread running argmin, reset acc
            const int nbase = (tile >> 4) * BN;
#pragma unroll
            for (int j = 0; j < 8; ++j) {
                const int n = nbase + ((j < 4) ? (4 * tx + j) : (64 + 4 * tx + j - 4));
                const float c2n = c2[n];
#pragma unroll
                for (int i = 0; i < 8; ++i) {
                    const float tv = fmaf(-2.f, acc[i][j], c2n);
                    if (tv < mint[i] || (tv == mint[i] && n < mink[i])) {
                        mint[i] = tv; mink[i] = n;
                    }
                    acc[i][j] = 0.f;
                }
            }
        }

        if (more) {
            writeLDS(buf ^ 1);
            __syncthreads();
        }
    }

    // cross-thread (over tx) argmin per point row via LDS
    __syncthreads();
#pragma unroll
    for (int i = 0; i < 8; ++i) {
        const int m = (i < 4) ? (4 * ty + i) : (64 + 4 * ty + i - 4);
        sm.red.t[m][tx] = mint[i];
        sm.red.k[m][tx] = mink[i];
    }
    __syncthreads();
    if (tid < BM) {
        const int m = tid;
        float bt = sm.red.t[m][0];
        int   bk = sm.red.k[m][0];
#pragma unroll
        for (int x = 1; x < 16; ++x) {
            const float tv = sm.red.t[m][x];
            const int   kv = sm.red.k[m][x];
            if (tv < bt || (tv == bt && kv < bk)) { bt = tv; bk = kv; }
        }
        o_assign[bm0 + m]  = (float)bk;
        ws_assign[bm0 + m] = bk;
        ws_tmin[bm0 + m]   = bt;
    }
}

// ---------------- counting sort: histogram
__global__ __launch_bounds__(256) void count_kernel(
    const int* __restrict__ assigni, int* __restrict__ counts)
{
    const int p = blockIdx.x * 256 + threadIdx.x;
    atomicAdd(&counts[assigni[p]], 1);
}

// ---------------- exclusive scan over Kn=1024 counts; also emits new_n
__global__ __launch_bounds__(1024) void scan_kernel(
    const int* __restrict__ counts, int* __restrict__ offsets,
    int* __restrict__ cursor, float* __restrict__ o_nn)
{
    __shared__ int s[Kn];
    const int t = threadIdx.x;
    const int c = counts[t];
    s[t] = c;
    o_nn[t] = (float)c;
    __syncthreads();
    for (int off = 1; off < Kn; off <<= 1) {
        const int u = (t >= off) ? s[t - off] : 0;
        __syncthreads();
        s[t] += u;
        __syncthreads();
    }
    const int excl = s[t] - c;
    offsets[t] = excl;
    cursor[t]  = excl;
}

// ---------------- scatter point ids into cluster buckets
__global__ __launch_bounds__(256) void scatter_kernel(
    const int* __restrict__ assigni, int* __restrict__ cursor,
    int* __restrict__ bucket)
{
    const int p = blockIdx.x * 256 + threadIdx.x;
    const int a = assigni[p];
    const int idx = atomicAdd(&cursor[a], 1);
    bucket[idx] = p;
}

// ---------------- per-point metrics: one wave per point (coalesced reads)
__global__ __launch_bounds__(256) void point_metrics_kernel(
    const float* __restrict__ points, const float* __restrict__ labels,
    const float* __restrict__ rlabels,
    const int* __restrict__ ws_assign, const float* __restrict__ ws_tmin,
    const float* __restrict__ rln,
    float* __restrict__ o_dist, float* __restrict__ o_disp,
    float* __restrict__ o_dlab, float* __restrict__ o_displab)
{
    const int tid  = threadIdx.x;
    const int lane = tid & 63;
    const int p    = blockIdx.x * 4 + (tid >> 6);
    const int a    = ws_assign[p];

    // point row: 64 lanes x float4 = 256 floats
    const float4 pv = ((const float4*)points)[(size_t)p * 64 + lane];
    float x2 = pv.x * pv.x + pv.y * pv.y + pv.z * pv.z + pv.w * pv.w;

    // label row reductions
    float l2 = 0.f, dt = 0.f;
    const float* lrow = labels  + (size_t)p * Ln;
    const float* crow = rlabels + (size_t)a * Ln;
    for (int i = lane; i < Ln; i += 64) {
        const float lv = lrow[i];
        const float cv = crow[i];
        l2 = fmaf(lv, lv, l2);
        dt = fmaf(lv, cv, dt);
    }

    for (int off = 32; off > 0; off >>= 1) {
        x2 += __shfl_down(x2, off, 64);
        l2 += __shfl_down(l2, off, 64);
        dt += __shfl_down(dt, off, 64);
    }

    if (lane == 0) {
        const float dist = x2 + ws_tmin[p];   // x2 - 2 p.c + c2
        o_dist[p] = dist;
        atomicAdd(&o_disp[a], dist);
        const float dl = 1.0f - dt / (sqrtf(l2) * rln[a] + EPSF);
        o_dlab[p] = dl;
        atomicAdd(&o_displab[a], dl);
    }
}

// ---------------- cluster sums: one block per cluster, column-partitioned.
// Zero atomics: gathers member rows (contiguous, coalesced) and writes sums.
__global__ __launch_bounds__(256) void cluster_sum_kernel(
    const float* __restrict__ points, const float* __restrict__ labels,
    const int* __restrict__ bucket, const int* __restrict__ offsets,
    const int* __restrict__ counts,
    float* __restrict__ o_nsum, float* __restrict__ o_nlab)
{
    const int k = blockIdx.x;
    const int t = threadIdx.x;
    const int beg = offsets[k];
    const int n   = counts[k];

    __shared__ int sidx[256];
    float accP  = 0.f;   // points column t
    float accL0 = 0.f;   // labels column t
    float accL1 = 0.f;   // labels column t+256
    float accL2 = 0.f;   // labels column t+512 (t < 14)

    for (int base = 0; base < n; base += 256) {
        const int m = min(256, n - base);
        __syncthreads();
        if (t < m) sidx[t] = bucket[beg + base + t];
        __syncthreads();
#pragma unroll 4
        for (int i = 0; i < m; ++i) {
            const int p = sidx[i];
            const float* pr = points + (size_t)p * Dn;
            const float* lr = labels + (size_t)p * Ln;
            accP  += pr[t];
            accL0 += lr[t];
            accL1 += lr[t + 256];
            if (t < Ln - 512) accL2 += lr[t + 512];
        }
    }

    o_nsum[(size_t)k * Dn + t] = accP;
    float* nl = o_nlab + (size_t)k * Ln;
    nl[t]       = accL0;
    nl[t + 256] = accL1;
    if (t < Ln - 512) nl[t + 512] = accL2;
}

extern "C" void kernel_launch(void* const* d_in, const int* in_sizes, int n_in,
                              void* d_out, int out_size, void* d_ws, size_t ws_size,
                              hipStream_t stream)
{
    const float* points    = (const float*)d_in[0];   // (B, D)
    const float* labels    = (const float*)d_in[1];   // (B, L)
    const float* centroids = (const float*)d_in[2];   // (K, D)
    const float* rlabels   = (const float*)d_in[3];   // (K, L)

    float* out = (float*)d_out;
    float* o_assign  = out;                       // B
    float* o_dist    = out + Bn;                  // B
    float* o_disp    = out + 2 * Bn;              // K
    float* o_dlab    = o_disp + Kn;               // B
    float* o_displab = o_dlab + Bn;               // K
    float* o_nsum    = o_displab + Kn;            // K*D
    float* o_nn      = o_nsum + Kn * Dn;          // K
    float* o_nlab    = o_nn + Kn;                 // K*L

    float* ws      = (float*)d_ws;
    float* c2      = ws;                          // Kn
    float* rln     = ws + Kn;                     // Kn
    float* tmin    = ws + 2 * Kn;                 // Bn
    int*   assigni = (int*)(ws + 2 * Kn + Bn);    // Bn
    int*   counts  = assigni + Bn;                // Kn
    int*   offsets = counts + Kn;                 // Kn
    int*   cursor  = offsets + Kn;                // Kn
    int*   bucket  = cursor + Kn;                 // Bn

    // zero only the atomic-accumulated regions (harness poisons with 0xAA)
    hipMemsetAsync(counts, 0, Kn * sizeof(int), stream);
    hipMemsetAsync(o_disp, 0, Kn * sizeof(float), stream);
    hipMemsetAsync(o_displab, 0, Kn * sizeof(float), stream);

    prep_kernel<<<Kn, 256, 0, stream>>>(centroids, rlabels, c2, rln);
    assign_kernel<<<Bn / BM, 256, 0, stream>>>(points, centroids, c2,
                                               o_assign, assigni, tmin);
    count_kernel<<<Bn / 256, 256, 0, stream>>>(assigni, counts);
    scan_kernel<<<1, Kn, 0, stream>>>(counts, offsets, cursor, o_nn);
    scatter_kernel<<<Bn / 256, 256, 0, stream>>>(assigni, cursor, bucket);
    point_metrics_kernel<<<Bn / 4, 256, 0, stream>>>(points, labels, rlabels,
                                                     assigni, tmin, rln,
                                                     o_dist, o_disp, o_dlab, o_displab);
    cluster_sum_kernel<<<Kn, 256, 0, stream>>>(points, labels, bucket, offsets,
                                               counts, o_nsum, o_nlab);
}

// Round 3
// 1410.846 us; speedup vs baseline: 2.3553x; 2.3553x over previous
//
#include <hip/hip_runtime.h>
#include <float.h>
#include <math.h>

// Problem constants (fixed by setup_inputs)
constexpr int Bn = 131072;  // points
constexpr int Dn = 256;     // feature dim
constexpr int Kn = 1024;    // clusters
constexpr int Ln = 526;     // label dim
constexpr float EPSF = 1e-8f;

constexpr int CHUNK = 128;                    // members per fused-kernel block
constexpr int MAXCHUNKS = Bn / CHUNK + Kn;    // 2048: sum ceil(n_k/C) <= B/C + K

// GEMM tiling for the assignment kernel
constexpr int BM = 128;     // points per block
constexpr int BN = 128;     // centroids per n-tile
constexpr int BK = 16;      // d-chunk
constexpr int LDT = 132;    // padded LDS row stride (floats) -> 2-way conflicts max
constexpr int NT = Kn / BN; // 8 n-tiles
constexpr int DC = Dn / BK; // 16 d-chunks
constexpr int NTILES = NT * DC; // 128

union SMemU {
    float tiles[2][2][BK][LDT];                 // [buf][A/B][d][m], 33792 B
    struct { float t[BM][16]; int k[BM][16]; } red;
};

// ---------------- prep: c2[k] = sum(centroids[k]^2), rln[k] = sqrt(sum(rl[k]^2))
__global__ __launch_bounds__(256) void prep_kernel(
    const float* __restrict__ centroids, const float* __restrict__ rlabels,
    float* __restrict__ c2, float* __restrict__ rln)
{
    const int k = blockIdx.x;
    const int t = threadIdx.x;
    float v = centroids[k * Dn + t];            // Dn == blockDim
    float s1 = v * v;
    float s2 = 0.f;
    for (int i = t; i < Ln; i += 256) {
        float u = rlabels[(size_t)k * Ln + i];
        s2 += u * u;
    }
    for (int off = 32; off > 0; off >>= 1) {
        s1 += __shfl_down(s1, off, 64);
        s2 += __shfl_down(s2, off, 64);
    }
    __shared__ float red[8];
    const int wv = t >> 6;
    if ((t & 63) == 0) { red[wv * 2] = s1; red[wv * 2 + 1] = s2; }
    __syncthreads();
    if (t == 0) {
        c2[k]  = red[0] + red[2] + red[4] + red[6];
        rln[k] = sqrtf(red[1] + red[3] + red[5] + red[7]);
    }
}

// ---------------- assignment: per-block 128 points x all 1024 centroids
// t(b,k) = c2[k] - 2*dot(p_b, c_k); argmin_k t == argmin_k dist (x2 is row-constant).
__global__ __launch_bounds__(256, 2) void assign_kernel(
    const float* __restrict__ points, const float* __restrict__ centroids,
    const float* __restrict__ c2,
    float* __restrict__ o_assign, int* __restrict__ ws_assign,
    float* __restrict__ ws_tmin)
{
    __shared__ SMemU sm;
    const int tid = threadIdx.x;
    const int tx = tid & 15;          // centroid group
    const int ty = tid >> 4;          // point group
    const int bm0 = blockIdx.x * BM;

    // staging mapping: each thread loads 2 float4 per matrix per tile
    const int r0 = tid >> 2;          // row 0..63
    const int g0 = tid & 3;           // d-group (float4)

    float acc[8][8];
#pragma unroll
    for (int i = 0; i < 8; ++i)
#pragma unroll
        for (int j = 0; j < 8; ++j) acc[i][j] = 0.f;

    float mint[8];
    int   mink[8];
#pragma unroll
    for (int i = 0; i < 8; ++i) { mint[i] = FLT_MAX; mink[i] = 0; }

    float4 pa0, pa1, pb0, pb1;        // prefetch regs

    auto prefetch = [&](int tile) {
        const int nt = tile >> 4, dc = tile & 15;
        const size_t dofs = dc * BK + g0 * 4;
        const float* ap = points    + (size_t)(bm0 + r0) * Dn + dofs;
        const float* bp = centroids + (size_t)(nt * BN + r0) * Dn + dofs;
        pa0 = *(const float4*)(ap);
        pa1 = *(const float4*)(ap + (size_t)64 * Dn);
        pb0 = *(const float4*)(bp);
        pb1 = *(const float4*)(bp + (size_t)64 * Dn);
    };
    auto writeLDS = [&](int buf) {
        float* As = &sm.tiles[buf][0][0][0];
        float* Bs = &sm.tiles[buf][1][0][0];
        const int c0 = g0 * 4;
        As[(c0 + 0) * LDT + r0]      = pa0.x;
        As[(c0 + 1) * LDT + r0]      = pa0.y;
        As[(c0 + 2) * LDT + r0]      = pa0.z;
        As[(c0 + 3) * LDT + r0]      = pa0.w;
        As[(c0 + 0) * LDT + r0 + 64] = pa1.x;
        As[(c0 + 1) * LDT + r0 + 64] = pa1.y;
        As[(c0 + 2) * LDT + r0 + 64] = pa1.z;
        As[(c0 + 3) * LDT + r0 + 64] = pa1.w;
        Bs[(c0 + 0) * LDT + r0]      = pb0.x;
        Bs[(c0 + 1) * LDT + r0]      = pb0.y;
        Bs[(c0 + 2) * LDT + r0]      = pb0.z;
        Bs[(c0 + 3) * LDT + r0]      = pb0.w;
        Bs[(c0 + 0) * LDT + r0 + 64] = pb1.x;
        Bs[(c0 + 1) * LDT + r0 + 64] = pb1.y;
        Bs[(c0 + 2) * LDT + r0 + 64] = pb1.z;
        Bs[(c0 + 3) * LDT + r0 + 64] = pb1.w;
    };

    prefetch(0);
    writeLDS(0);
    __syncthreads();

    for (int tile = 0; tile < NTILES; ++tile) {
        const int buf = tile & 1;
        const bool more = (tile + 1) < NTILES;
        if (more) prefetch(tile + 1);

        const float* As = &sm.tiles[buf][0][0][0];
        const float* Bs = &sm.tiles[buf][1][0][0];
#pragma unroll
        for (int c = 0; c < BK; ++c) {
            const float4 a0 = *(const float4*)(As + c * LDT + 4 * ty);
            const float4 a1 = *(const float4*)(As + c * LDT + 64 + 4 * ty);
            const float4 b0 = *(const float4*)(Bs + c * LDT + 4 * tx);
            const float4 b1 = *(const float4*)(Bs + c * LDT + 64 + 4 * tx);
            const float av[8] = {a0.x, a0.y, a0.z, a0.w, a1.x, a1.y, a1.z, a1.w};
            const float bv[8] = {b0.x, b0.y, b0.z, b0.w, b1.x, b1.y, b1.z, b1.w};
#pragma unroll
            for (int i = 0; i < 8; ++i)
#pragma unroll
                for (int j = 0; j < 8; ++j)
                    acc[i][j] = fmaf(av[i], bv[j], acc[i][j]);
        }

        if ((tile & 15) == 15) {
            // n-tile complete: fold into per-thread running argmin, reset acc
            const int nbase = (tile >> 4) * BN;
#pragma unroll
            for (int j = 0; j < 8; ++j) {
                const int n = nbase + ((j < 4) ? (4 * tx + j) : (64 + 4 * tx + j - 4));
                const float c2n = c2[n];
#pragma unroll
                for (int i = 0; i < 8; ++i) {
                    const float tv = fmaf(-2.f, acc[i][j], c2n);
                    if (tv < mint[i] || (tv == mint[i] && n < mink[i])) {
                        mint[i] = tv; mink[i] = n;
                    }
                    acc[i][j] = 0.f;
                }
            }
        }

        if (more) {
            writeLDS(buf ^ 1);
            __syncthreads();
        }
    }

    // cross-thread (over tx) argmin per point row via LDS
    __syncthreads();
#pragma unroll
    for (int i = 0; i < 8; ++i) {
        const int m = (i < 4) ? (4 * ty + i) : (64 + 4 * ty + i - 4);
        sm.red.t[m][tx] = mint[i];
        sm.red.k[m][tx] = mink[i];
    }
    __syncthreads();
    if (tid < BM) {
        const int m = tid;
        float bt = sm.red.t[m][0];
        int   bk = sm.red.k[m][0];
#pragma unroll
        for (int x = 1; x < 16; ++x) {
            const float tv = sm.red.t[m][x];
            const int   kv = sm.red.k[m][x];
            if (tv < bt || (tv == bt && kv < bk)) { bt = tv; bk = kv; }
        }
        o_assign[bm0 + m]  = (float)bk;
        ws_assign[bm0 + m] = bk;
        ws_tmin[bm0 + m]   = bt;
    }
}

// ---------------- counting sort: histogram
__global__ __launch_bounds__(256) void count_kernel(
    const int* __restrict__ assigni, int* __restrict__ counts)
{
    const int p = blockIdx.x * 256 + threadIdx.x;
    atomicAdd(&counts[assigni[p]], 1);
}

// ---------------- exclusive scans over Kn=1024: counts and chunk counts
__global__ __launch_bounds__(1024) void scan_kernel(
    const int* __restrict__ counts, int* __restrict__ offsets,
    int* __restrict__ cursor, float* __restrict__ o_nn,
    int* __restrict__ chunk_off)
{
    __shared__ int s[Kn];
    const int t = threadIdx.x;
    const int c = counts[t];
    o_nn[t] = (float)c;
    s[t] = c;
    __syncthreads();
    for (int off = 1; off < Kn; off <<= 1) {
        const int u = (t >= off) ? s[t - off] : 0;
        __syncthreads();
        s[t] += u;
        __syncthreads();
    }
    const int excl = s[t] - c;
    offsets[t] = excl;
    cursor[t]  = excl;

    // second scan: chunks per cluster
    const int cc = (c + CHUNK - 1) / CHUNK;
    __syncthreads();
    s[t] = cc;
    __syncthreads();
    for (int off = 1; off < Kn; off <<= 1) {
        const int u = (t >= off) ? s[t - off] : 0;
        __syncthreads();
        s[t] += u;
        __syncthreads();
    }
    chunk_off[t] = s[t] - cc;
    if (t == Kn - 1) chunk_off[Kn] = s[t];
}

// ---------------- scatter point ids into cluster buckets
__global__ __launch_bounds__(256) void scatter_kernel(
    const int* __restrict__ assigni, int* __restrict__ cursor,
    int* __restrict__ bucket)
{
    const int p = blockIdx.x * 256 + threadIdx.x;
    const int a = assigni[p];
    const int idx = atomicAdd(&cursor[a], 1);
    bucket[idx] = p;
}

// ---------------- fused gather: per-chunk member-parallel, wave-per-member.
// Computes dist/dist_labels per member, dispersions + new_sum/new_labels partials.
__global__ __launch_bounds__(256) void fused_cluster_kernel(
    const float* __restrict__ points, const float* __restrict__ labels,
    const float* __restrict__ rlabels,
    const int* __restrict__ bucket, const int* __restrict__ offsets,
    const int* __restrict__ counts, const int* __restrict__ chunk_off,
    const float* __restrict__ tmin, const float* __restrict__ rln,
    float* __restrict__ o_dist, float* __restrict__ o_disp,
    float* __restrict__ o_dlab, float* __restrict__ o_displab,
    float* __restrict__ o_nsum, float* __restrict__ o_nlab)
{
    const int b = blockIdx.x;
    if (b >= chunk_off[Kn]) return;           // uniform early-exit

    // binary search: largest k with chunk_off[k] <= b
    int lo = 0, hi = Kn;
    while (hi - lo > 1) {
        const int mid = (lo + hi) >> 1;
        if (chunk_off[mid] <= b) lo = mid; else hi = mid;
    }
    const int k   = lo;
    const int j   = b - chunk_off[k];
    const int nk  = counts[k];
    const int beg = offsets[k] + j * CHUNK;
    const int nm  = min(nk - j * CHUNK, CHUNK);
    const bool single = (nk <= CHUNK);

    const int tid  = threadIdx.x;
    const int lane = tid & 63;
    const int w    = tid >> 6;

    __shared__ int   sidx[CHUNK];
    __shared__ __align__(16) float srl[528];   // cluster's rlabel row
    __shared__ float sacc[784];                // 256 point cols + 526 label cols
    __shared__ float sdisp[4], sdlab[4];

    for (int i = tid; i < nm; i += 256) sidx[i] = bucket[beg + i];
    for (int i = tid; i < Ln; i += 256) srl[i] = rlabels[(size_t)k * Ln + i];
    for (int i = tid; i < 784; i += 256) sacc[i] = 0.f;
    __syncthreads();

    // loop-invariant rlabel fragments for this lane (float2 layout)
    const float2 rl0 = *(const float2*)&srl[2 * lane];
    const float2 rl1 = *(const float2*)&srl[2 * (64 + lane)];
    const float2 rl2 = *(const float2*)&srl[2 * (128 + lane)];
    const float2 rl3 = *(const float2*)&srl[2 * (192 + lane)];
    float2 rlT = make_float2(0.f, 0.f);
    if (lane < 7) rlT = *(const float2*)&srl[2 * (256 + lane)];
    const float rlnk = rln[k];

    float4 accP  = make_float4(0.f, 0.f, 0.f, 0.f);
    float2 accL0 = make_float2(0.f, 0.f), accL1 = accL0,
           accL2 = accL0, accL3 = accL0, accLT = accL0;
    float dispacc = 0.f, displabacc = 0.f;

    // register double-buffered member loop: wave w handles members w, w+4, ...
    float4 pv0; float2 a0, b0_, c0, d0, e0; int p0 = 0; float t0 = 0.f;
    auto loadM = [&](int i, float4& pv, float2& a, float2& bb, float2& cc,
                     float2& dd, float2& ee, int& pid, float& tm) {
        pid = sidx[i];
        pv = ((const float4*)(points + (size_t)pid * Dn))[lane];
        const float2* l2p = (const float2*)(labels + (size_t)pid * Ln);
        a  = l2p[lane];
        bb = l2p[64 + lane];
        cc = l2p[128 + lane];
        dd = l2p[192 + lane];
        ee = (lane < 7) ? l2p[256 + lane] : make_float2(0.f, 0.f);
        tm = (lane == 0) ? tmin[pid] : 0.f;
    };

    int i = w;
    if (i < nm) loadM(i, pv0, a0, b0_, c0, d0, e0, p0, t0);
    while (i < nm) {
        const int inext = i + 4;
        float4 pv1; float2 a1, b1_, c1, d1, e1; int p1 = 0; float t1 = 0.f;
        if (inext < nm) loadM(inext, pv1, a1, b1_, c1, d1, e1, p1, t1);

        // accumulate column sums
        accP.x += pv0.x; accP.y += pv0.y; accP.z += pv0.z; accP.w += pv0.w;
        accL0.x += a0.x;  accL0.y += a0.y;
        accL1.x += b0_.x; accL1.y += b0_.y;
        accL2.x += c0.x;  accL2.y += c0.y;
        accL3.x += d0.x;  accL3.y += d0.y;
        accLT.x += e0.x;  accLT.y += e0.y;

        // per-member reductions
        float x2m = pv0.x * pv0.x + pv0.y * pv0.y + pv0.z * pv0.z + pv0.w * pv0.w;
        float l2m = a0.x * a0.x + a0.y * a0.y + b0_.x * b0_.x + b0_.y * b0_.y
                  + c0.x * c0.x + c0.y * c0.y + d0.x * d0.x + d0.y * d0.y
                  + e0.x * e0.x + e0.y * e0.y;
        float dtm = a0.x * rl0.x + a0.y * rl0.y + b0_.x * rl1.x + b0_.y * rl1.y
                  + c0.x * rl2.x + c0.y * rl2.y + d0.x * rl3.x + d0.y * rl3.y
                  + e0.x * rlT.x + e0.y * rlT.y;
#pragma unroll
        for (int off = 1; off < 64; off <<= 1) {
            x2m += __shfl_xor(x2m, off, 64);
            l2m += __shfl_xor(l2m, off, 64);
            dtm += __shfl_xor(dtm, off, 64);
        }
        if (lane == 0) {
            const float dist = x2m + t0;                 // x2 - 2 p.c + c2
            o_dist[p0] = dist;
            const float dl = 1.0f - dtm / (sqrtf(l2m) * rlnk + EPSF);
            o_dlab[p0] = dl;
            dispacc += dist;
            displabacc += dl;
        }

        pv0 = pv1; a0 = a1; b0_ = b1_; c0 = c1; d0 = d1; e0 = e1;
        p0 = p1; t0 = t1;
        i = inext;
    }

    if (lane == 0) { sdisp[w] = dispacc; sdlab[w] = displabacc; }

    // cross-wave column reduction (sequential waves, 4 barriers)
    for (int ww = 0; ww < 4; ++ww) {
        __syncthreads();
        if (w == ww) {
            float* sp = sacc;
            sp[4 * lane + 0] += accP.x;
            sp[4 * lane + 1] += accP.y;
            sp[4 * lane + 2] += accP.z;
            sp[4 * lane + 3] += accP.w;
            float* sl = sacc + 256;
            sl[2 * lane]           += accL0.x; sl[2 * lane + 1]       += accL0.y;
            sl[128 + 2 * lane]     += accL1.x; sl[128 + 2 * lane + 1] += accL1.y;
            sl[256 + 2 * lane]     += accL2.x; sl[256 + 2 * lane + 1] += accL2.y;
            sl[384 + 2 * lane]     += accL3.x; sl[384 + 2 * lane + 1] += accL3.y;
            if (lane < 7) {
                sl[512 + 2 * lane]     += accLT.x;
                sl[512 + 2 * lane + 1] += accLT.y;
            }
        }
    }
    __syncthreads();

    // write block partials (direct store if this cluster has a single chunk)
    float* np = o_nsum + (size_t)k * Dn;
    float* nl = o_nlab + (size_t)k * Ln;
    const float vP  = sacc[tid];
    const float vL0 = sacc[256 + tid];
    const float vL1 = sacc[512 + tid];
    if (single) {
        np[tid]       = vP;
        nl[tid]       = vL0;
        nl[tid + 256] = vL1;
        if (tid < 14) nl[tid + 512] = sacc[768 + tid];
    } else {
        atomicAdd(&np[tid], vP);
        atomicAdd(&nl[tid], vL0);
        atomicAdd(&nl[tid + 256], vL1);
        if (tid < 14) atomicAdd(&nl[tid + 512], sacc[768 + tid]);
    }
    if (tid == 0) {
        const float dsum  = sdisp[0] + sdisp[1] + sdisp[2] + sdisp[3];
        const float dlsum = sdlab[0] + sdlab[1] + sdlab[2] + sdlab[3];
        if (single) { o_disp[k] = dsum; o_displab[k] = dlsum; }
        else { atomicAdd(&o_disp[k], dsum); atomicAdd(&o_displab[k], dlsum); }
    }
}

extern "C" void kernel_launch(void* const* d_in, const int* in_sizes, int n_in,
                              void* d_out, int out_size, void* d_ws, size_t ws_size,
                              hipStream_t stream)
{
    const float* points    = (const float*)d_in[0];   // (B, D)
    const float* labels    = (const float*)d_in[1];   // (B, L)
    const float* centroids = (const float*)d_in[2];   // (K, D)
    const float* rlabels   = (const float*)d_in[3];   // (K, L)

    float* out = (float*)d_out;
    float* o_assign  = out;                       // B
    float* o_dist    = out + Bn;                  // B
    float* o_disp    = out + 2 * Bn;              // K
    float* o_dlab    = o_disp + Kn;               // B
    float* o_displab = o_dlab + Bn;               // K
    float* o_nsum    = o_displab + Kn;            // K*D
    float* o_nn      = o_nsum + Kn * Dn;          // K
    float* o_nlab    = o_nn + Kn;                 // K*L

    float* ws        = (float*)d_ws;
    float* c2        = ws;                          // Kn
    float* rln       = ws + Kn;                     // Kn
    float* tmin      = ws + 2 * Kn;                 // Bn
    int*   assigni   = (int*)(ws + 2 * Kn + Bn);    // Bn
    int*   counts    = assigni + Bn;                // Kn
    int*   offsets   = counts + Kn;                 // Kn
    int*   cursor    = offsets + Kn;                // Kn
    int*   bucket    = cursor + Kn;                 // Bn
    int*   chunk_off = bucket + Bn;                 // Kn+1

    // zero atomic-accumulated regions (harness poisons with 0xAA)
    hipMemsetAsync(counts, 0, Kn * sizeof(int), stream);
    hipMemsetAsync(o_disp, 0, Kn * sizeof(float), stream);
    hipMemsetAsync(o_displab, 0, Kn * sizeof(float), stream);
    hipMemsetAsync(o_nsum, 0, (size_t)Kn * Dn * sizeof(float), stream);
    hipMemsetAsync(o_nlab, 0, (size_t)Kn * Ln * sizeof(float), stream);

    prep_kernel<<<Kn, 256, 0, stream>>>(centroids, rlabels, c2, rln);
    assign_kernel<<<Bn / BM, 256, 0, stream>>>(points, centroids, c2,
                                               o_assign, assigni, tmin);
    count_kernel<<<Bn / 256, 256, 0, stream>>>(assigni, counts);
    scan_kernel<<<1, Kn, 0, stream>>>(counts, offsets, cursor, o_nn, chunk_off);
    scatter_kernel<<<Bn / 256, 256, 0, stream>>>(assigni, cursor, bucket);
    fused_cluster_kernel<<<MAXCHUNKS, 256, 0, stream>>>(
        points, labels, rlabels, bucket, offsets, counts, chunk_off,
        tmin, rln, o_dist, o_disp, o_dlab, o_displab, o_nsum, o_nlab);
}